// Round 1
// baseline (15830.792 us; speedup 1.0000x reference)
//
#include <hip/hip_runtime.h>

#define TSTEPS 512
#define BATCH  32
#define DIM    256
#define UNITS  256
#define NBLK   256   // 128 per direction
#define UPB    2     // units per block
#define GATES  4
#define COLS4U 1024  // 4*UNITS

__device__ __forceinline__ float fsig(float x) { return 1.0f / (1.0f + __expf(-x)); }
__device__ __forceinline__ float ftanh(float x) {
  float xx = fminf(fmaxf(x, -15.0f), 15.0f);
  float e = __expf(2.0f * xx);
  return (e - 1.0f) / (e + 1.0f);
}

__global__ __launch_bounds__(256, 1) void bilstm_scan(
    const float* __restrict__ x,
    const float* __restrict__ Wk_f, const float* __restrict__ Wr_f,
    const float* __restrict__ b_f,
    const float* __restrict__ Wk_b, const float* __restrict__ Wr_b,
    const float* __restrict__ b_b,
    float* __restrict__ out, float* __restrict__ hbuf,
    unsigned* __restrict__ bar)
{
  const int bid  = blockIdx.x;
  const int dir  = bid >> 7;        // 0 = forward, 1 = backward
  const int sub  = bid & 127;
  const int u0   = sub * UPB;
  const int tid  = threadIdx.x;
  const int g    = tid >> 6;        // wave id = gate id (i,f,g,o)
  const int lane = tid & 63;
  const int b    = lane >> 1;
  const int u    = lane & 1;
  const int col  = g * UNITS + u0 + u;   // column in [0, 1024)

  const float* Wk   = dir ? Wk_b : Wk_f;
  const float* Wr   = dir ? Wr_b : Wr_f;
  const float* bias = dir ? b_b  : b_f;

  __shared__ float wk_lds[8][DIM];   // [c8 = g*2+u][k]
  __shared__ float wr_lds[8][DIM];
  __shared__ float z_lds[GATES][64];

  // Stage this block's 8 W columns (transposed) into LDS. One-time cost.
  for (int idx = tid; idx < 8 * DIM; idx += 256) {
    int c8 = idx >> 8;          // 0..7
    int k  = idx & (DIM - 1);
    int gg = c8 >> 1, uu = c8 & 1;
    int cc = gg * UNITS + u0 + uu;
    wk_lds[c8][k] = Wk[k * COLS4U + cc];
    wr_lds[c8][k] = Wr[k * COLS4U + cc];
  }
  __syncthreads();

  const int   c8   = g * 2 + u;
  const float bcol = bias[col];

  float* hdir = hbuf + dir * (2 * BATCH * UNITS);
  float  c_reg = 0.0f;          // meaningful only for tid < 64
  bool   bar_ok = true;         // spin-timeout safety valve (tid 0 only)

  for (int t = 0; t < TSTEPS; ++t) {
    const float* hcur = hdir + (t & 1) * (BATCH * UNITS);
    float*       hnxt = hdir + ((t + 1) & 1) * (BATCH * UNITS);
    const int tin = dir ? (TSTEPS - 1 - t) : t;

    const float4* xrow = (const float4*)(x + ((size_t)b * TSTEPS + tin) * DIM);
    const float4* hrow = (const float4*)(hcur + b * UNITS);
    const float4* wk4  = (const float4*)wk_lds[c8];
    const float4* wr4  = (const float4*)wr_lds[c8];

    float4 ax = make_float4(0.f, 0.f, 0.f, 0.f);
    float4 ah = make_float4(0.f, 0.f, 0.f, 0.f);
#pragma unroll 8
    for (int k = 0; k < DIM / 4; ++k) {
      float4 xv = xrow[k];
      float4 wkv = wk4[k];
      float4 hv = hrow[k];
      float4 wrv = wr4[k];
      ax.x = fmaf(xv.x, wkv.x, ax.x);
      ax.y = fmaf(xv.y, wkv.y, ax.y);
      ax.z = fmaf(xv.z, wkv.z, ax.z);
      ax.w = fmaf(xv.w, wkv.w, ax.w);
      ah.x = fmaf(hv.x, wrv.x, ah.x);
      ah.y = fmaf(hv.y, wrv.y, ah.y);
      ah.z = fmaf(hv.z, wrv.z, ah.z);
      ah.w = fmaf(hv.w, wrv.w, ah.w);
    }
    float z = bcol + (ax.x + ax.y + ax.z + ax.w) + (ah.x + ah.y + ah.z + ah.w);
    z_lds[g][lane] = z;
    __syncthreads();

    if (tid < 64) {
      float zi = z_lds[0][lane];
      float zf = z_lds[1][lane];
      float zg = z_lds[2][lane];
      float zo = z_lds[3][lane];
      float iv = fsig(zi), fv = fsig(zf), gv = ftanh(zg), ov = fsig(zo);
      c_reg = fv * c_reg + iv * gv;
      float hval = ov * ftanh(c_reg);
      hnxt[b * UNITS + u0 + u] = hval;
      const int tout = dir ? (TSTEPS - 1 - t) : t;
      out[((size_t)b * TSTEPS + tout) * (2 * UNITS) + dir * UNITS + u0 + u] = hval;
      if (t == TSTEPS - 1) {
        out[(size_t)BATCH * TSTEPS * (2 * UNITS) + (size_t)b * (2 * UNITS)
            + dir * UNITS + u0 + u] = hval;
      }
    }
    __syncthreads();   // hnxt stores done block-wide; z_lds safe to reuse

    if (t < TSTEPS - 1) {
      if (tid == 0) {
        __threadfence();   // make this block's hnxt stores agent-visible
        __hip_atomic_fetch_add(bar, 1u, __ATOMIC_RELEASE, __HIP_MEMORY_SCOPE_AGENT);
        const unsigned target = (unsigned)NBLK * (unsigned)(t + 1);
        if (bar_ok) {
          unsigned spins = 0;
          while (__hip_atomic_load(bar, __ATOMIC_RELAXED, __HIP_MEMORY_SCOPE_AGENT) < target) {
            __builtin_amdgcn_s_sleep(1);
            if (++spins > (1u << 20)) { bar_ok = false; break; }
          }
        }
        __threadfence();   // acquire side: invalidate stale cached h
      }
      __syncthreads();
    }
  }
}

extern "C" void kernel_launch(void* const* d_in, const int* in_sizes, int n_in,
                              void* d_out, int out_size, void* d_ws, size_t ws_size,
                              hipStream_t stream) {
  const float* x    = (const float*)d_in[0];
  const float* Wk_f = (const float*)d_in[1];
  const float* Wr_f = (const float*)d_in[2];
  const float* b_f  = (const float*)d_in[3];
  const float* Wk_b = (const float*)d_in[4];
  const float* Wr_b = (const float*)d_in[5];
  const float* b_b  = (const float*)d_in[6];
  float* out = (float*)d_out;

  // ws layout: hbuf[2 dirs][2 ping-pong][32][256] f32 = 128 KiB, then barrier counter
  const size_t HBUF_BYTES = (size_t)2 * 2 * BATCH * UNITS * sizeof(float);
  float*    hbuf = (float*)d_ws;
  unsigned* bar  = (unsigned*)((char*)d_ws + HBUF_BYTES);

  // zero h ping-pong buffers + barrier counter (deterministic per launch / replay)
  hipMemsetAsync(d_ws, 0, HBUF_BYTES + 128, stream);

  bilstm_scan<<<NBLK, 256, 0, stream>>>(x, Wk_f, Wr_f, b_f, Wk_b, Wr_b, b_b,
                                        out, hbuf, bar);
}

// Round 2
// 2399.291 us; speedup vs baseline: 6.5981x; 6.5981x over previous
//
#include <hip/hip_runtime.h>

#define T_STEPS 512
#define BATCH   32
#define DIM     256
#define UNITS   256
#define COLS4U  1024

typedef _Float16 half8 __attribute__((ext_vector_type(8)));
typedef float    f32x4 __attribute__((ext_vector_type(4)));
typedef float    f32x4n __attribute__((ext_vector_type(4)));
typedef unsigned long long ull;
typedef ull      ull2  __attribute__((ext_vector_type(2)));

__device__ __forceinline__ float fsig(float x){ return 1.0f/(1.0f+__expf(-x)); }
__device__ __forceinline__ float ftanh(float x){
  float xx = fminf(fmaxf(x,-15.f),15.f);
  float e = __expf(2.f*xx);
  return (e-1.f)/(e+1.f);
}

// byte offset into a [32][256] f16 LDS plane, XOR-swizzled 16B granules:
// granule g = u>>3, slot within 128B period = (g&7)^(b&7)  -> <=2-way conflicts
__device__ __forceinline__ int swz(int b, int u){
  int g = u >> 3;
  int s = (g & 7) ^ (b & 7);
  return b*512 + (g>>3)*128 + s*16 + (u & 7)*2;
}

__global__ __launch_bounds__(256,1) void bilstm_mfma(
    const float* __restrict__ x,
    const float* __restrict__ Wk_f, const float* __restrict__ Wr_f, const float* __restrict__ b_f,
    const float* __restrict__ Wk_b, const float* __restrict__ Wr_b, const float* __restrict__ b_b,
    float* __restrict__ out,
    unsigned short* __restrict__ slices,   // [2 parity][2 dir][4 blk][32][64] f16 bits
    unsigned* __restrict__ flags)          // [2 dir][4 blk], stride 32 uints (128B)
{
  const int dir = blockIdx.x >> 2;       // 0 fwd, 1 bwd
  const int g4  = blockIdx.x & 3;        // unit-group within direction
  const int tid = threadIdx.x;
  const int w   = tid >> 6;              // wave 0..3
  const int lane= tid & 63;
  const int l15 = lane & 15;
  const int l4  = lane >> 4;

  const float* Wk = dir ? Wk_b : Wk_f;
  const float* Wr = dir ? Wr_b : Wr_f;
  const float* bs = dir ? b_b  : b_f;

  const int u0b   = g4*64;               // this block's unit base (64 units)
  const int upl   = u0b + w*16 + l15;    // plane-local unit col (0..255), n = lane&15
  const int outcol= dir*256 + upl;

  __shared__ _Float16 xlds[BATCH*DIM];        // x_t, fp16, swizzled
  __shared__ _Float16 hlds[2][BATCH*UNITS];   // h ping-pong, fp16, swizzled

  // ---------------- one-time: weights -> registers (B fragments) ----------------
  // B-frag for mfma_16x16x32_f16: n = lane&15, k = (lane>>4)*8 + r (k-perm cancels vs A)
  half8 Bf[4][16];   // [gate q][k-tile kk: 0..7 = Wk, 8..15 = Wr]
#pragma unroll
  for (int q=0;q<4;q++){
    const int col = q*256 + upl;
#pragma unroll
    for (int kk=0;kk<16;kk++){
      const float* Ws = (kk<8) ? Wk : Wr;
      const int k0 = (kk&7)*32 + l4*8;
      half8 v;
#pragma unroll
      for (int r=0;r<8;r++) v[r] = (_Float16)Ws[(size_t)(k0+r)*COLS4U + col];
      Bf[q][kk] = v;
      __builtin_amdgcn_sched_barrier(0);   // cap preload register pressure
    }
  }

  float bias[4];
#pragma unroll
  for (int q=0;q<4;q++) bias[q] = bs[q*256 + upl];

  // zero h plane 0 (linear fill is fine: zeros everywhere)
  {
    half8 z;
#pragma unroll
    for (int e=0;e<8;e++) z[e] = (_Float16)0.f;
    for (int i=tid; i<BATCH*UNITS/8; i+=256) ((half8*)hlds[0])[i] = z;
  }

  // stage x_0 into LDS
  const int bx  = tid >> 3;          // batch row this thread stages
  const int d0x = (tid & 7) * 32;    // 32 contiguous d per thread
  float xr[32];
  {
    const int tin0 = dir ? (T_STEPS-1) : 0;
    const float* xp = x + ((size_t)bx*T_STEPS + tin0)*DIM + d0x;
#pragma unroll
    for (int i=0;i<8;i++){
      f32x4 v = *(const f32x4*)(xp + i*4);
      xr[i*4+0]=v[0]; xr[i*4+1]=v[1]; xr[i*4+2]=v[2]; xr[i*4+3]=v[3];
    }
#pragma unroll
    for (int j=0;j<4;j++){
      half8 hh;
#pragma unroll
      for (int e=0;e<8;e++) hh[e] = (_Float16)xr[j*8+e];
      *(half8*)((char*)xlds + swz(bx, d0x + j*8)) = hh;
    }
  }
  __syncthreads();

  float cst[8];
#pragma unroll
  for (int i=0;i<8;i++) cst[i]=0.f;
  bool spin_ok = true;

  for (int t=0; t<T_STEPS; ++t){
    // ---- P1: issue x_{t+1} prefetch (consumed in P5) ----
    if (t+1 < T_STEPS){
      const int tin = dir ? (T_STEPS-2-t) : (t+1);
      const float* xp = x + ((size_t)bx*T_STEPS + tin)*DIM + d0x;
#pragma unroll
      for (int i=0;i<8;i++){
        f32x4 v = *(const f32x4*)(xp + i*4);
        xr[i*4+0]=v[0]; xr[i*4+1]=v[1]; xr[i*4+2]=v[2]; xr[i*4+3]=v[3];
      }
    }

    // ---- P2: z = [x_t | h_t] @ [Wk; Wr] slice, MFMA, acc init = bias ----
    f32x4 acc[2][4];
#pragma unroll
    for (int q=0;q<4;q++){
      f32x4 a; a[0]=bias[q]; a[1]=bias[q]; a[2]=bias[q]; a[3]=bias[q];
      acc[0][q]=a; acc[1][q]=a;
    }
    const char* hpl = (const char*)hlds[t&1];
#pragma unroll
    for (int kk=0;kk<16;kk++){
      const char* pl = (kk<8) ? (const char*)xlds : hpl;
      const int ul = (kk&7)*32 + l4*8;
      half8 a0 = *(const half8*)(pl + swz(l15,      ul));
      half8 a1 = *(const half8*)(pl + swz(16+l15,   ul));
#pragma unroll
      for (int q=0;q<4;q++){
        acc[0][q] = __builtin_amdgcn_mfma_f32_16x16x32_f16(a0, Bf[q][kk], acc[0][q], 0,0,0);
        acc[1][q] = __builtin_amdgcn_mfma_f32_16x16x32_f16(a1, Bf[q][kk], acc[1][q], 0,0,0);
      }
    }

    // ---- P3: gates -> c,h (all in registers; D: n=lane&15, m=(lane>>4)*4+r) ----
    const int tout = dir ? (T_STEPS-1-t) : t;
    unsigned short* slc = slices + (((size_t)((t+1)&1))*8 + dir*4 + g4)*2048;
    char* hnx = (char*)hlds[(t+1)&1];
#pragma unroll
    for (int mt=0; mt<2; mt++){
#pragma unroll
      for (int r=0;r<4;r++){
        const int b = mt*16 + l4*4 + r;
        float iv = fsig (acc[mt][0][r]);
        float fv = fsig (acc[mt][1][r]);
        float gv = ftanh(acc[mt][2][r]);
        float ov = fsig (acc[mt][3][r]);
        float &c = cst[mt*4+r];
        c = fv*c + iv*gv;
        float hv = ov*ftanh(c);
        out[((size_t)b*T_STEPS + tout)*(2*UNITS) + outcol] = hv;
        if (t == T_STEPS-1)
          out[(size_t)BATCH*T_STEPS*(2*UNITS) + (size_t)b*(2*UNITS) + outcol] = hv;
        _Float16 hf = (_Float16)hv;
        *(_Float16*)(hnx + swz(b, upl)) = hf;      // own slice -> next h plane
        if (t+1 < T_STEPS)
          __hip_atomic_store(&slc[b*64 + (w*16+l15)],
                             __builtin_bit_cast(unsigned short, hf),
                             __ATOMIC_RELAXED, __HIP_MEMORY_SCOPE_AGENT);
      }
    }
    __syncthreads();   // drains each wave's vmcnt -> slice stores are at coherence point

    // ---- P5: publish flag, stage x_{t+1}, fetch 3 peer slices ----
    if (t+1 < T_STEPS){
      if (tid == 192)   // wave 3 lane 0 (wave 3 has no spin role)
        __hip_atomic_store(&flags[(dir*4+g4)*32], (unsigned)(t+1),
                           __ATOMIC_RELAXED, __HIP_MEMORY_SCOPE_AGENT);
#pragma unroll
      for (int j=0;j<4;j++){
        half8 hh;
#pragma unroll
        for (int e=0;e<8;e++) hh[e] = (_Float16)xr[j*8+e];
        *(half8*)((char*)xlds + swz(bx, d0x + j*8)) = hh;
      }
      if (w < 3){
        const int p = w + (w >= g4);          // peer block id within direction
        const unsigned target = (unsigned)(t+1);
        if (spin_ok){
          int sp = 0;
          while (__hip_atomic_load(&flags[(dir*4+p)*32],
                                   __ATOMIC_RELAXED, __HIP_MEMORY_SCOPE_AGENT) < target){
            if (++sp > (1<<22)) { spin_ok = false; break; }   // never hang
          }
        }
        const ull* src = (const ull*)(slices + (((size_t)((t+1)&1))*8 + dir*4 + p)*2048);
        const int bsl = lane >> 1;
        const int u00 = (lane & 1) * 32;
#pragma unroll
        for (int j=0;j<4;j++){
          ull v0 = __hip_atomic_load(&src[lane*8 + 2*j  ], __ATOMIC_RELAXED, __HIP_MEMORY_SCOPE_AGENT);
          ull v1 = __hip_atomic_load(&src[lane*8 + 2*j+1], __ATOMIC_RELAXED, __HIP_MEMORY_SCOPE_AGENT);
          ull2 vv; vv[0]=v0; vv[1]=v1;
          *(ull2*)(hnx + swz(bsl, p*64 + u00 + j*8)) = vv;
        }
      }
      __syncthreads();
    }
  }
}

extern "C" void kernel_launch(void* const* d_in, const int* in_sizes, int n_in,
                              void* d_out, int out_size, void* d_ws, size_t ws_size,
                              hipStream_t stream) {
  const float* x    = (const float*)d_in[0];
  const float* Wk_f = (const float*)d_in[1];
  const float* Wr_f = (const float*)d_in[2];
  const float* b_f  = (const float*)d_in[3];
  const float* Wk_b = (const float*)d_in[4];
  const float* Wr_b = (const float*)d_in[5];
  const float* b_b  = (const float*)d_in[6];
  float* out = (float*)d_out;

  // ws: slices [2 parity][8 block-slots][2048 ushort] = 64 KiB, then flags (1 KiB)
  unsigned short* slices = (unsigned short*)d_ws;
  unsigned* flags = (unsigned*)((char*)d_ws + 65536);

  hipMemsetAsync((char*)d_ws + 65536, 0, 1024, stream);   // flags = 0 each launch

  bilstm_mfma<<<8, 256, 0, stream>>>(x, Wk_f, Wr_f, b_f, Wk_b, Wr_b, b_b,
                                     out, slices, flags);
}